// Round 4
// baseline (1362.281 us; speedup 1.0000x reference)
//
#include <hip/hip_runtime.h>
#include <cmath>

#define DEV __device__ __forceinline__

constexpr int T_TOK   = 3072;
constexpr int D_MODEL = 1536;
constexpr int FRAMES  = 6;
constexpr int NH      = 12;
constexpr int HD      = 128;
constexpr int FF_DIM  = 8960;
constexpr int TC      = 512;
constexpr float EPS_F = 1e-6f;
constexpr float ATT_SCALE = 0.08838834764831845f; // 1/sqrt(128)

typedef short bf16x8 __attribute__((ext_vector_type(8)));
typedef float f32x4  __attribute__((ext_vector_type(4)));

DEV ushort f2bf(float f) {
  unsigned u = __builtin_bit_cast(unsigned, f);
  unsigned r = u + 0x7fff + ((u >> 16) & 1);
  return (ushort)(r >> 16);
}

DEV unsigned packbf2(float lo, float hi) {
  return (unsigned)f2bf(lo) | ((unsigned)f2bf(hi) << 16);
}

DEV void gload16(const void* g, void* l) {
  __builtin_amdgcn_global_load_lds(
      (const __attribute__((address_space(1))) void*)g,
      (__attribute__((address_space(3))) void*)l, 16, 0, 0);
}

// ---------------------------------------------------------------------------
__global__ __launch_bounds__(256) void mod_kernel(
    const float* __restrict__ modulation, const float* __restrict__ t_mod,
    float* __restrict__ modbuf) {
  int i = blockIdx.x * 256 + threadIdx.x;
  if (i >= FRAMES * 6 * D_MODEL) return;
  int d  = i % D_MODEL;
  int mi = (i / D_MODEL) % 6;
  modbuf[i] = modulation[mi * D_MODEL + d] + t_mod[i];
}

// fp32 -> bf16 elementwise (n4 = count/4)
__global__ __launch_bounds__(256) void cvt_bf16_kernel(
    const float* __restrict__ in, ushort* __restrict__ out, int n4) {
  int i = blockIdx.x * 256 + threadIdx.x;
  if (i >= n4) return;
  float4 v = ((const float4*)in)[i];
  ushort4 o;
  o.x = f2bf(v.x); o.y = f2bf(v.y); o.z = f2bf(v.z); o.w = f2bf(v.w);
  ((ushort4*)out)[i] = o;
}

// W(K,N) fp32 -> Wt(N,K) bf16. grid (N/64, K/64), block 256.
__global__ __launch_bounds__(256) void wconv_kernel(
    const float* __restrict__ W, ushort* __restrict__ Wt, int K, int N) {
  __shared__ float tile[64][65];
  const int k0 = blockIdx.y * 64, n0 = blockIdx.x * 64;
  const int t = threadIdx.x;
  const int r = t >> 4, c4 = (t & 15) * 4;
#pragma unroll
  for (int i = 0; i < 4; ++i) {
    float4 v = *(const float4*)&W[(long)(k0 + r + 16 * i) * N + n0 + c4];
    tile[r + 16 * i][c4 + 0] = v.x; tile[r + 16 * i][c4 + 1] = v.y;
    tile[r + 16 * i][c4 + 2] = v.z; tile[r + 16 * i][c4 + 3] = v.w;
  }
  __syncthreads();
  const int orow = t >> 5, oc2 = (t & 31) * 2;
#pragma unroll
  for (int j = 0; j < 8; ++j) {
    int nrow = orow + 8 * j;
    ushort2 o;
    o.x = f2bf(tile[oc2][nrow]);
    o.y = f2bf(tile[oc2 + 1][nrow]);
    *(ushort2*)&Wt[(long)(n0 + nrow) * K + k0 + oc2] = o;
  }
}

// transpose fp32 strided slice [Tv][1536] -> bf16 Vt[1536][Tv]. grid (Tv/64, 1536/64)
__global__ __launch_bounds__(256) void vtrans_kernel(
    const float* __restrict__ V, int stride, int Tv, ushort* __restrict__ Vt) {
  __shared__ float tile[64][65];
  const int t0 = blockIdx.x * 64, d0 = blockIdx.y * 64;
  const int t = threadIdx.x;
  const int r = t >> 4, c4 = (t & 15) * 4;
#pragma unroll
  for (int i = 0; i < 4; ++i) {
    float4 v = *(const float4*)&V[(long)(t0 + r + 16 * i) * stride + d0 + c4];
    tile[r + 16 * i][c4 + 0] = v.x; tile[r + 16 * i][c4 + 1] = v.y;
    tile[r + 16 * i][c4 + 2] = v.z; tile[r + 16 * i][c4 + 3] = v.w;
  }
  __syncthreads();
  const int od = t >> 2, tc = (t & 3) * 16;
#pragma unroll
  for (int j4 = 0; j4 < 4; ++j4) {
    ushort4 o;
    o.x = f2bf(tile[tc + j4 * 4 + 0][od]);
    o.y = f2bf(tile[tc + j4 * 4 + 1][od]);
    o.z = f2bf(tile[tc + j4 * 4 + 2][od]);
    o.w = f2bf(tile[tc + j4 * 4 + 3][od]);
    *(ushort4*)&Vt[(long)(d0 + od) * Tv + t0 + tc + j4 * 4] = o;
  }
}

// ---------------------------------------------------------------------------
DEV void block_reduce2(float& s, float& s2, float* red, int t) {
  int lane = t & 63, w = t >> 6;
#pragma unroll
  for (int o = 32; o > 0; o >>= 1) {
    s  += __shfl_down(s,  o, 64);
    s2 += __shfl_down(s2, o, 64);
  }
  if (lane == 0) { red[w] = s; red[4 + w] = s2; }
  __syncthreads();
  s  = (red[0] + red[1]) + (red[2] + red[3]);
  s2 = (red[4] + red[5]) + (red[6] + red[7]);
}

// LN (no affine) then y*(1+sc)+sh, bf16 output
__global__ __launch_bounds__(256) void ln_mod_kernel(
    const float* __restrict__ x, const float* __restrict__ modbuf,
    int ish, int isc, ushort* __restrict__ out) {
  __shared__ float red[8];
  int row = blockIdx.x, t = threadIdx.x;
  const float* xr = x + (long)row * D_MODEL;
  float vals[6];
  float s = 0.f, s2 = 0.f;
#pragma unroll
  for (int i = 0; i < 6; ++i) {
    float v = xr[t + 256 * i];
    vals[i] = v; s += v; s2 += v * v;
  }
  block_reduce2(s, s2, red, t);
  float mean = s * (1.f / D_MODEL);
  float var  = s2 * (1.f / D_MODEL) - mean * mean;
  float rs   = 1.f / sqrtf(var + EPS_F);
  const float* mb = modbuf + (long)(row >> 9) * 6 * D_MODEL;
#pragma unroll
  for (int i = 0; i < 6; ++i) {
    int d = t + 256 * i;
    float y = (vals[i] - mean) * rs;
    out[(long)row * D_MODEL + d] = f2bf(y * (1.f + mb[isc * D_MODEL + d]) + mb[ish * D_MODEL + d]);
  }
}

// LN with affine w,b, bf16 output
__global__ __launch_bounds__(256) void ln_affine_kernel(
    const float* __restrict__ x, const float* __restrict__ w,
    const float* __restrict__ b, ushort* __restrict__ out) {
  __shared__ float red[8];
  int row = blockIdx.x, t = threadIdx.x;
  const float* xr = x + (long)row * D_MODEL;
  float vals[6];
  float s = 0.f, s2 = 0.f;
#pragma unroll
  for (int i = 0; i < 6; ++i) {
    float v = xr[t + 256 * i];
    vals[i] = v; s += v; s2 += v * v;
  }
  block_reduce2(s, s2, red, t);
  float mean = s * (1.f / D_MODEL);
  float var  = s2 * (1.f / D_MODEL) - mean * mean;
  float rs   = 1.f / sqrtf(var + EPS_F);
#pragma unroll
  for (int i = 0; i < 6; ++i) {
    int d = t + 256 * i;
    float y = (vals[i] - mean) * rs;
    out[(long)row * D_MODEL + d] = f2bf(y * w[d] + b[d]);
  }
}

// RMS norm over D of strided fp32 rows -> packed bf16 [rows][D_MODEL]; optional RoPE
template <bool ROPE>
__global__ __launch_bounds__(256) void rmsbf_kernel(
    const float* __restrict__ in, int stride, const float* __restrict__ w,
    const float* __restrict__ cosb, const float* __restrict__ sinb,
    ushort* __restrict__ out) {
  __shared__ float red[8];
  int row = blockIdx.x, t = threadIdx.x;
  const float* xr = in + (long)row * stride;
  float vals[6];
  float s2 = 0.f, dummy = 0.f;
#pragma unroll
  for (int i = 0; i < 6; ++i) {
    float v = xr[t + 256 * i];
    vals[i] = v; s2 += v * v;
  }
  block_reduce2(s2, dummy, red, t);
  float rs = 1.f / sqrtf(s2 * (1.f / D_MODEL) + EPS_F);
  ushort* orow = out + (long)row * D_MODEL;
  if (ROPE) {
#pragma unroll
    for (int pi = 0; pi < 3; ++pi) {
      int p = t + 256 * pi;            // 0..767
      int hh = p >> 6, ii = p & 63;
      int d0 = hh * HD + 2 * ii;
      float a = xr[d0] * rs * w[d0];
      float b = xr[d0 + 1] * rs * w[d0 + 1];
      float c = cosb[(long)row * 64 + ii];
      float sn = sinb[(long)row * 64 + ii];
      ushort2 o;
      o.x = f2bf(a * c - b * sn);
      o.y = f2bf(a * sn + b * c);
      *(ushort2*)&orow[d0] = o;
    }
  } else {
#pragma unroll
    for (int i = 0; i < 6; ++i) {
      int d = t + 256 * i;
      orow[d] = f2bf(vals[i] * rs * w[d]);
    }
  }
}

// ---------------------------------------------------------------------------
// bf16 MFMA GEMM (m97 structure): C[M,N] = epi(A[M,K] @ Bt[N,K]^T + bias)
template <int EPI>
__global__ __launch_bounds__(256) void mgemm_kernel(
    const ushort* __restrict__ A, const ushort* __restrict__ Bt,
    const float* __restrict__ bias, const float* __restrict__ res,
    const float* __restrict__ modbuf, int gidx,
    void* __restrict__ Cout, int M, int N, int K, int ldc) {
  __shared__ ushort As[128 * 32];
  __shared__ ushort Bs[128 * 32];
  const int t = threadIdx.x;
  const int bm = blockIdx.y * 128, bn = blockIdx.x * 128;
  const int wave = t >> 6, lane = t & 63;
  const int wr = (wave >> 1) * 64, wc = (wave & 1) * 64;
  const int l15 = lane & 15, l4 = lane >> 4;

  f32x4 acc[4][4] = {};

  const int srow  = t >> 2;
  const int skoff = (t & 3) * 8;
  const ushort* Ag = A  + (long)(bm + srow) * K + skoff;
  const ushort* Bg = Bt + (long)(bn + srow) * K + skoff;
  ushort* Asl = As + t * 8;
  ushort* Bsl = Bs + t * 8;
  const long half = (long)64 * K;

  for (int k0 = 0; k0 < K; k0 += 32) {
    __syncthreads();
    gload16(Ag + k0, Asl);
    gload16(Ag + k0 + half, Asl + 2048);
    gload16(Bg + k0, Bsl);
    gload16(Bg + k0 + half, Bsl + 2048);
    asm volatile("s_waitcnt vmcnt(0)" ::: "memory");
    __syncthreads();
    bf16x8 af[4], bfr[4];
#pragma unroll
    for (int m = 0; m < 4; ++m)
      af[m] = *(const bf16x8*)&As[(wr + m * 16 + l15) * 32 + l4 * 8];
#pragma unroll
    for (int n = 0; n < 4; ++n)
      bfr[n] = *(const bf16x8*)&Bs[(wc + n * 16 + l15) * 32 + l4 * 8];
#pragma unroll
    for (int m = 0; m < 4; ++m)
#pragma unroll
      for (int n = 0; n < 4; ++n)
        acc[m][n] = __builtin_amdgcn_mfma_f32_16x16x32_bf16(af[m], bfr[n], acc[m][n], 0, 0, 0);
  }

#pragma unroll
  for (int m = 0; m < 4; ++m) {
#pragma unroll
    for (int r = 0; r < 4; ++r) {
      const int grow = bm + wr + m * 16 + l4 * 4 + r;
      const long rowoff = (long)grow * ldc;
      const float* mrow = nullptr;
      if (EPI == 2) mrow = modbuf + (long)((grow >> 9) * 6 + gidx) * D_MODEL;
#pragma unroll
      for (int n = 0; n < 4; ++n) {
        const int gcol = bn + wc + n * 16 + l15;
        float val = acc[m][n][r] + bias[gcol];
        if (EPI == 0) {
          ((float*)Cout)[rowoff + gcol] = val;
        } else if (EPI == 1) {
          float u = val;
          val = u / (1.f + __expf(-1.5957691216057308f * (u + 0.044715f * u * u * u)));
          ((ushort*)Cout)[rowoff + gcol] = f2bf(val);
        } else if (EPI == 2) {
          ((float*)Cout)[rowoff + gcol] = res[rowoff + gcol] + val * mrow[gcol];
        } else {
          ((float*)Cout)[rowoff + gcol] = res[rowoff + gcol] + val;
        }
      }
    }
  }
}

// ---------------------------------------------------------------------------
// Barrier-free bf16 MFMA flash attention.
// Qb,Kb: [T][D_MODEL] bf16. Vt: [NH*HD][Tk] bf16 (transposed).
// Flat grid 288 blocks; block = 4 independent waves, each owning 32 q-rows.
// Swapped QK^T (S^T = mfma(K,Q)) makes softmax reductions lane-local (+2 shfl).
// K/V fragments read directly from global (L2-resident); only P uses LDS
// (per-wave, no __syncthreads anywhere).
template <bool CAUSAL>
__global__ __launch_bounds__(256) void mattn_kernel(
    const ushort* __restrict__ Qb, const ushort* __restrict__ Kb,
    const ushort* __restrict__ Vt, ushort* __restrict__ O, int Tk) {
  __shared__ ushort Pl[4][32 * 72];   // per-wave P[32 q][64 k], row stride 72
  const int t = threadIdx.x;
  // XCD-aware remap (288 = 8 xcd * 36): cluster each head's blocks on <=2 XCDs,
  // long frames dispatched first (qb descending) for tail balance.
  const int bid = blockIdx.x;
  const int L = (bid & 7) * 36 + (bid >> 3);
  const int h  = L / 24;
  const int q0 = (23 - (L % 24)) * 128;
  const int wave = t >> 6;
  const int l15 = t & 15, l4 = (t >> 4) & 3;
  const int wq = wave * 32;
  const int kmax = CAUSAL ? (((q0 >> 9) + 1) << 9) : Tk;
  const float SC2 = ATT_SCALE * 1.4426950408889634f;  // fold log2(e): exp2 domain

  // Q fragments (B-operand): lane l15 = q-row, contraction d = ks*32 + l4*8
  bf16x8 qf[2][4];
#pragma unroll
  for (int mf = 0; mf < 2; ++mf)
#pragma unroll
    for (int ks = 0; ks < 4; ++ks)
      qf[mf][ks] = *(const bf16x8*)&Qb[(long)(q0 + wq + mf * 16 + l15) * D_MODEL + h * HD + ks * 32 + l4 * 8];

  f32x4 ao[2][8] = {};
  float m_run[2] = {-1e30f, -1e30f};
  float l_run[2] = {0.f, 0.f};

  const ushort* Kh = Kb + h * HD;
  const ushort* Vh = Vt + (long)h * HD * Tk;
  ushort*   Plw   = &Pl[wave][0];
  unsigned* Plw32 = (unsigned*)Plw;

  for (int k0 = 0; k0 < kmax; k0 += 64) {
    // K fragments (A-operand): lane l15 = k-row
    bf16x8 kf[4][4];
#pragma unroll
    for (int n = 0; n < 4; ++n)
#pragma unroll
      for (int ks = 0; ks < 4; ++ks)
        kf[n][ks] = *(const bf16x8*)&Kh[(long)(k0 + n * 16 + l15) * D_MODEL + ks * 32 + l4 * 8];

    // S^T[k][q]: lane l15 = q, reg r -> k = n*16 + l4*4 + r
    f32x4 s[2][4] = {};
#pragma unroll
    for (int n = 0; n < 4; ++n)
#pragma unroll
      for (int mf = 0; mf < 2; ++mf)
#pragma unroll
        for (int ks = 0; ks < 4; ++ks)
          s[mf][n] = __builtin_amdgcn_mfma_f32_16x16x32_bf16(kf[n][ks], qf[mf][ks], s[mf][n], 0, 0, 0);

    // V fragments issued early; latency hides under softmax
    bf16x8 vf[8][2];
#pragma unroll
    for (int nd = 0; nd < 8; ++nd)
#pragma unroll
      for (int ks2 = 0; ks2 < 2; ++ks2)
        vf[nd][ks2] = *(const bf16x8*)&Vh[(long)(nd * 16 + l15) * Tk + k0 + ks2 * 32 + l4 * 8];

    // online softmax (exp2 domain); per-lane 16 values, 2 shfl per reduction
#pragma unroll
    for (int mf = 0; mf < 2; ++mf) {
      float mx = s[mf][0][0];
#pragma unroll
      for (int n = 0; n < 4; ++n)
#pragma unroll
        for (int r = 0; r < 4; ++r) mx = fmaxf(mx, s[mf][n][r]);
      mx *= SC2;
      mx = fmaxf(mx, __shfl_xor(mx, 16, 64));
      mx = fmaxf(mx, __shfl_xor(mx, 32, 64));
      float mnew = fmaxf(m_run[mf], mx);
      float al = exp2f(m_run[mf] - mnew);
      m_run[mf] = mnew;
      float p[4][4];
      float ps = 0.f;
#pragma unroll
      for (int n = 0; n < 4; ++n)
#pragma unroll
        for (int r = 0; r < 4; ++r) {
          p[n][r] = exp2f(s[mf][n][r] * SC2 - mnew);
          ps += p[n][r];
        }
      ps += __shfl_xor(ps, 16, 64);
      ps += __shfl_xor(ps, 32, 64);
      l_run[mf] = l_run[mf] * al + ps;
      // write P row q=mf*16+l15: k-words 8n+2*l4, packed (r0,r1)(r2,r3)
#pragma unroll
      for (int n = 0; n < 4; ++n) {
        uint2 wv;
        wv.x = packbf2(p[n][0], p[n][1]);
        wv.y = packbf2(p[n][2], p[n][3]);
        *(uint2*)&Plw32[(mf * 16 + l15) * 36 + n * 8 + l4 * 2] = wv;
      }
      // alpha for accumulator rows q = l4*4+r
      float alq[4];
#pragma unroll
      for (int r = 0; r < 4; ++r) alq[r] = __shfl(al, l4 * 4 + r, 64);
#pragma unroll
      for (int nd = 0; nd < 8; ++nd)
#pragma unroll
        for (int r = 0; r < 4; ++r) ao[mf][nd][r] *= alq[r];
    }

    // PV: A = P (from per-wave LDS), B = V^T (regs)
    bf16x8 paf[2][2];
#pragma unroll
    for (int mf = 0; mf < 2; ++mf)
#pragma unroll
      for (int ks2 = 0; ks2 < 2; ++ks2)
        paf[mf][ks2] = *(const bf16x8*)&Plw[(mf * 16 + l15) * 72 + ks2 * 32 + l4 * 8];
#pragma unroll
    for (int nd = 0; nd < 8; ++nd)
#pragma unroll
      for (int ks2 = 0; ks2 < 2; ++ks2)
#pragma unroll
        for (int mf = 0; mf < 2; ++mf)
          ao[mf][nd] = __builtin_amdgcn_mfma_f32_16x16x32_bf16(paf[mf][ks2], vf[nd][ks2], ao[mf][nd], 0, 0, 0);
  }

  // epilogue: O /= l, bf16 out
#pragma unroll
  for (int mf = 0; mf < 2; ++mf) {
#pragma unroll
    for (int r = 0; r < 4; ++r) {
      float linv = 1.f / __shfl(l_run[mf], l4 * 4 + r, 64);
      long rb = (long)(q0 + wq + mf * 16 + l4 * 4 + r) * D_MODEL + h * HD + l15;
#pragma unroll
      for (int nd = 0; nd < 8; ++nd)
        O[rb + nd * 16] = f2bf(ao[mf][nd][r] * linv);
    }
  }
}

// ---------------------------------------------------------------------------
extern "C" void kernel_launch(void* const* d_in, const int* in_sizes, int n_in,
                              void* d_out, int out_size, void* d_ws, size_t ws_size,
                              hipStream_t stream) {
  const float* x      = (const float*)d_in[0];
  const float* ctx    = (const float*)d_in[1];
  const float* t_mod  = (const float*)d_in[2];
  const float* fcos   = (const float*)d_in[3];
  const float* fsin   = (const float*)d_in[4];
  const float* sa_wq = (const float*)d_in[5];  const float* sa_bq = (const float*)d_in[6];
  const float* sa_wk = (const float*)d_in[7];  const float* sa_bk = (const float*)d_in[8];
  const float* sa_wv = (const float*)d_in[9];  const float* sa_bv = (const float*)d_in[10];
  const float* sa_wo = (const float*)d_in[11]; const float* sa_bo = (const float*)d_in[12];
  const float* sa_nq = (const float*)d_in[13]; const float* sa_nk = (const float*)d_in[14];
  const float* ca_wq = (const float*)d_in[15]; const float* ca_bq = (const float*)d_in[16];
  const float* ca_wk = (const float*)d_in[17]; const float* ca_bk = (const float*)d_in[18];
  const float* ca_wv = (const float*)d_in[19]; const float* ca_bv = (const float*)d_in[20];
  const float* ca_wo = (const float*)d_in[21]; const float* ca_bo = (const float*)d_in[22];
  const float* ca_nq = (const float*)d_in[23]; const float* ca_nk = (const float*)d_in[24];
  const float* n3w = (const float*)d_in[25]; const float* n3b = (const float*)d_in[26];
  const float* w1 = (const float*)d_in[27]; const float* b1 = (const float*)d_in[28];
  const float* w2 = (const float*)d_in[29]; const float* b2 = (const float*)d_in[30];
  const float* modulation = (const float*)d_in[31];
  (void)in_sizes; (void)n_in; (void)out_size; (void)ws_size;

  float* out = (float*)d_out;
  char*  wsb = (char*)d_ws;

  // ---- workspace layout (bytes) ----
  float*  modbuf  = (float*)(wsb + 0);            //    221,184
  float*  biascat = (float*)(wsb + 221184);       //     30,720
  ushort* wscr    = (ushort*)(wsb + 251904);      // 27,525,120 weight scratch
  ushort* inp     = (ushort*)(wsb + 27777024);    //  9,437,184 T*D bf16
  char*   R       = wsb + 37214208;               // 56,623,104 multi-use
  ushort* attb    = (ushort*)(wsb + 93837312);    //  9,437,184
  ushort* Qbb     = (ushort*)(wsb + 103274496);   //  9,437,184 self/cross Q bf16
  char*   KV      = wsb + 112711680;              // 18,874,368 self K/Vt bf16; later x1
  char*   M       = wsb + 131586048;              //  3,145,728 ctxb | cross Kb + cross Vt
  // total 134,731,776 B

  float*  qkvb = (float*)R;                        // self: T x 4608 fp32
  float*  qc   = (float*)R;                        // cross: T x 1536 fp32
  float*  kvc  = (float*)(R + 18874368);           // cross: Tc x 3072 fp32
  ushort* hb   = (ushort*)R;                       // mlp:  T x FF bf16
  ushort* Kbb  = (ushort*)KV;                      // self K bf16 [T][D]
  ushort* Vtb  = (ushort*)(KV + 9437184);          // self Vt bf16 [1536][T]
  float*  x1   = (float*)KV;                       // residual after self (and after cross, in-place)
  ushort* ctxb = (ushort*)M;                       // ctx bf16 (dead after cross-KV gemm)
  ushort* Kbc  = (ushort*)M;                       // cross K bf16 [Tc][D] (overlays ctxb)
  ushort* Vtc  = (ushort*)(M + 1572864);           // cross Vt bf16 [1536][Tc]

  dim3 b256(256);
  dim3 gT(T_TOK);
  dim3 gattn(T_TOK / 128 * NH);                    // 288 flat, remapped in-kernel
  const long WQ = (long)D_MODEL * D_MODEL;

  mod_kernel<<<dim3((FRAMES * 6 * D_MODEL + 255) / 256), b256, 0, stream>>>(modulation, t_mod, modbuf);
  hipMemcpyAsync(biascat + 0,    sa_bq, 6144, hipMemcpyDeviceToDevice, stream);
  hipMemcpyAsync(biascat + 1536, sa_bk, 6144, hipMemcpyDeviceToDevice, stream);
  hipMemcpyAsync(biascat + 3072, sa_bv, 6144, hipMemcpyDeviceToDevice, stream);
  hipMemcpyAsync(biascat + 4608, ca_bk, 6144, hipMemcpyDeviceToDevice, stream);
  hipMemcpyAsync(biascat + 6144, ca_bv, 6144, hipMemcpyDeviceToDevice, stream);
  cvt_bf16_kernel<<<dim3(TC * D_MODEL / 4 / 256), b256, 0, stream>>>(ctx, ctxb, TC * D_MODEL / 4);

  dim3 gw(D_MODEL / 64, D_MODEL / 64);

  // ===== self-attention branch =====
  ln_mod_kernel<<<gT, b256, 0, stream>>>(x, modbuf, 0, 1, inp);
  wconv_kernel<<<gw, b256, 0, stream>>>(sa_wq, wscr + 0 * WQ, D_MODEL, D_MODEL);
  wconv_kernel<<<gw, b256, 0, stream>>>(sa_wk, wscr + 1 * WQ, D_MODEL, D_MODEL);
  wconv_kernel<<<gw, b256, 0, stream>>>(sa_wv, wscr + 2 * WQ, D_MODEL, D_MODEL);
  mgemm_kernel<0><<<dim3(4608 / 128, T_TOK / 128), b256, 0, stream>>>(
      inp, wscr, biascat, nullptr, nullptr, 0, qkvb, T_TOK, 4608, D_MODEL, 4608);
  rmsbf_kernel<true><<<gT, b256, 0, stream>>>(qkvb, 4608, sa_nq, fcos, fsin, Qbb);
  rmsbf_kernel<true><<<gT, b256, 0, stream>>>(qkvb + 1536, 4608, sa_nk, fcos, fsin, Kbb);
  vtrans_kernel<<<dim3(T_TOK / 64, D_MODEL / 64), b256, 0, stream>>>(qkvb + 3072, 4608, T_TOK, Vtb);
  mattn_kernel<true><<<gattn, b256, 0, stream>>>(Qbb, Kbb, Vtb, attb, T_TOK);
  wconv_kernel<<<gw, b256, 0, stream>>>(sa_wo, wscr, D_MODEL, D_MODEL);
  mgemm_kernel<2><<<dim3(D_MODEL / 128, T_TOK / 128), b256, 0, stream>>>(
      attb, wscr, sa_bo, x, modbuf, 2, x1, T_TOK, D_MODEL, D_MODEL, D_MODEL);

  // ===== cross-attention branch =====
  ln_affine_kernel<<<gT, b256, 0, stream>>>(x1, n3w, n3b, inp);
  wconv_kernel<<<gw, b256, 0, stream>>>(ca_wq, wscr, D_MODEL, D_MODEL);
  mgemm_kernel<0><<<dim3(D_MODEL / 128, T_TOK / 128), b256, 0, stream>>>(
      inp, wscr, ca_bq, nullptr, nullptr, 0, qc, T_TOK, D_MODEL, D_MODEL, D_MODEL);
  rmsbf_kernel<false><<<gT, b256, 0, stream>>>(qc, 1536, ca_nq, nullptr, nullptr, Qbb);
  wconv_kernel<<<gw, b256, 0, stream>>>(ca_wk, wscr + 0 * WQ, D_MODEL, D_MODEL);
  wconv_kernel<<<gw, b256, 0, stream>>>(ca_wv, wscr + 1 * WQ, D_MODEL, D_MODEL);
  mgemm_kernel<0><<<dim3(3072 / 128, TC / 128), b256, 0, stream>>>(
      ctxb, wscr, biascat + 4608, nullptr, nullptr, 0, kvc, TC, 3072, D_MODEL, 3072);
  rmsbf_kernel<false><<<dim3(TC), b256, 0, stream>>>(kvc, 3072, ca_nk, nullptr, nullptr, Kbc);
  vtrans_kernel<<<dim3(TC / 64, D_MODEL / 64), b256, 0, stream>>>(kvc + 1536, 3072, TC, Vtc);
  mattn_kernel<false><<<gattn, b256, 0, stream>>>(Qbb, Kbc, Vtc, attb, TC);
  wconv_kernel<<<gw, b256, 0, stream>>>(ca_wo, wscr, D_MODEL, D_MODEL);
  mgemm_kernel<3><<<dim3(D_MODEL / 128, T_TOK / 128), b256, 0, stream>>>(
      attb, wscr, ca_bo, x1, nullptr, 0, x1, T_TOK, D_MODEL, D_MODEL, D_MODEL);

  // ===== MLP branch =====
  ln_mod_kernel<<<gT, b256, 0, stream>>>(x1, modbuf, 3, 4, inp);
  wconv_kernel<<<dim3(FF_DIM / 64, D_MODEL / 64), b256, 0, stream>>>(w1, wscr, D_MODEL, FF_DIM);
  mgemm_kernel<1><<<dim3(FF_DIM / 128, T_TOK / 128), b256, 0, stream>>>(
      inp, wscr, b1, nullptr, nullptr, 0, hb, T_TOK, FF_DIM, D_MODEL, FF_DIM);
  wconv_kernel<<<dim3(D_MODEL / 64, FF_DIM / 64), b256, 0, stream>>>(w2, wscr, FF_DIM, D_MODEL);
  mgemm_kernel<2><<<dim3(D_MODEL / 128, T_TOK / 128), b256, 0, stream>>>(
      hb, wscr, b2, x1, modbuf, 5, out, T_TOK, D_MODEL, FF_DIM, D_MODEL);
}